// Round 13
// baseline (146.104 us; speedup 1.0000x reference)
//
#include <hip/hip_runtime.h>
#include <math.h>

#define BB 128
#define NN 256
#define WW 64
#define DD 128
#define KK 20
#define LL (BB*WW)   // 8192

// ================= Kernel 1: MEGA (all covpre-independent work in one launch) =================
// paths by blockIdx.x:
//   [0, 3*split)            cov partial tiles: 128x128 upper-tri tiles {(0,0),(0,1),(1,1)},
//                           acc[8][8] fp32 (xl2 skeleton: 0.0625 ds_read/FMA vs old 0.19)
//   [3*split, 3*split+256)  xl = x @ lin_W (+ raw att dots -> sil/sjl, WITHOUT eem: race-free)
//   [.., +256)              mean + diag (fp64 sum + sum-of-squares per node row)
//   [.., +128)              emb stats (eemi/eemj/nrm2), 2 nodes per block
__global__ __launch_bounds__(256) void k_mega(const float* __restrict__ data,
                                              const float* __restrict__ emb,
                                              const float* __restrict__ linW,
                                              const float* __restrict__ att_i,
                                              const float* __restrict__ att_j,
                                              const float* __restrict__ att_em_i,
                                              const float* __restrict__ att_em_j,
                                              float* __restrict__ covp,
                                              double* __restrict__ mean,
                                              double* __restrict__ diagc,
                                              float* __restrict__ eemi,
                                              float* __restrict__ eemj,
                                              double* __restrict__ nrm2,
                                              float* __restrict__ xl,
                                              float* __restrict__ sil,
                                              float* __restrict__ sjl,
                                              int split, int bpc) {
    __shared__ float As[128][68];   // 34 KB (also Xs for xl path)
    __shared__ float Bs[128][68];   // 34 KB (also Wt for xl path)
    const int t = threadIdx.x;      // 256 threads
    const int bx = blockIdx.x;
    const int ncov = 3 * split;

    if (bx < ncov) {
        // ---------------- cov partial path ----------------
        const int tile = bx / split, bz = bx % split;
        const int bi = (tile == 2) ? 1 : 0;
        const int bj = (tile == 0) ? 0 : 1;
        const int i0 = bi * 128, j0 = bj * 128;
        const int ti = t >> 4, tj = t & 15;

        float acc[8][8] = {};
        const int b0 = bz * bpc;

        #pragma unroll 1
        for (int cb = 0; cb < bpc; ++cb) {
            const int b = b0 + cb;
            #pragma unroll
            for (int e = 0; e < 8; ++e) {
                int idx = t + e * 256, row = idx >> 4, q = idx & 15;
                *(float4*)&As[row][4 * q] =
                    ((const float4*)(data + ((size_t)b * NN + i0 + row) * WW))[q];
                *(float4*)&Bs[row][4 * q] =
                    ((const float4*)(data + ((size_t)b * NN + j0 + row) * WW))[q];
            }
            __syncthreads();
            #pragma unroll
            for (int q = 0; q < 16; ++q) {
                float4 wb[8];
                #pragma unroll
                for (int c = 0; c < 8; ++c) wb[c] = *(const float4*)&Bs[tj + 16 * c][4 * q];
                #pragma unroll
                for (int r = 0; r < 8; ++r) {
                    float4 xa = *(const float4*)&As[8 * ti + r][4 * q];
                    #pragma unroll
                    for (int c = 0; c < 8; ++c)
                        acc[r][c] += xa.x * wb[c].x + xa.y * wb[c].y
                                   + xa.z * wb[c].z + xa.w * wb[c].w;
                }
            }
            __syncthreads();
        }
        #pragma unroll
        for (int r = 0; r < 8; ++r)
            #pragma unroll
            for (int c = 0; c < 8; ++c)
                covp[((size_t)bz * NN + i0 + 8 * ti + r) * NN + j0 + tj + 16 * c] = acc[r][c];
        return;
    }

    if (bx < ncov + 256) {
        // ---------------- xl + raw att-dots path ----------------
        const int r0 = (bx - ncov) * 128;
        const int ti = t >> 4, tj = t & 15;

        #pragma unroll
        for (int e = 0; e < 8; ++e) {
            int idx = t + e * 256, row = idx >> 4, q = idx & 15;
            *(float4*)&As[row][4 * q] =
                ((const float4*)(data + (size_t)(r0 + row) * WW))[q];
        }
        #pragma unroll
        for (int e = 0; e < 32; ++e) {
            int idx = t + e * 256;        // idx = k*128 + col
            int k = idx >> 7, col = idx & 127;
            Bs[col][k] = linW[idx];       // Wt[col][k]
        }
        __syncthreads();

        float acc[8][8] = {};             // rows 8*ti+r, cols tj+16*c
        #pragma unroll
        for (int q = 0; q < 16; ++q) {
            float4 wb[8];
            #pragma unroll
            for (int c = 0; c < 8; ++c) wb[c] = *(const float4*)&Bs[tj + 16 * c][4 * q];
            #pragma unroll
            for (int r = 0; r < 8; ++r) {
                float4 xa = *(const float4*)&As[8 * ti + r][4 * q];
                #pragma unroll
                for (int c = 0; c < 8; ++c)
                    acc[r][c] += xa.x * wb[c].x + xa.y * wb[c].y
                               + xa.z * wb[c].z + xa.w * wb[c].w;
            }
        }
        #pragma unroll
        for (int r = 0; r < 8; ++r)
            #pragma unroll
            for (int c = 0; c < 8; ++c)
                xl[(size_t)(r0 + 8 * ti + r) * DD + tj + 16 * c] = acc[r][c];

        float ai[8], aj[8];
        #pragma unroll
        for (int c = 0; c < 8; ++c) { ai[c] = att_i[tj + 16 * c]; aj[c] = att_j[tj + 16 * c]; }
        #pragma unroll
        for (int r = 0; r < 8; ++r) {
            float pi = 0.f, pj = 0.f;
            #pragma unroll
            for (int c = 0; c < 8; ++c) { pi += acc[r][c] * ai[c]; pj += acc[r][c] * aj[c]; }
            #pragma unroll
            for (int m = 8; m; m >>= 1) { pi += __shfl_xor(pi, m); pj += __shfl_xor(pj, m); }
            if (tj == 0) {
                int v = r0 + 8 * ti + r;
                sil[v] = pi;              // eem terms added in k_attn3 (avoids intra-kernel race)
                sjl[v] = pj;
            }
        }
        return;
    }

    const int pb = bx - ncov - 256;
    const int lane = t & 63, wid = t >> 6;
    if (pb < NN) {
        // ---------------- mean + diag path ----------------
        int n = pb;
        double s = 0.0, s2 = 0.0;
        for (int c = 0; c < LL / 256; ++c) {
            int l = t + c * 256;
            int b = l >> 6, w = l & 63;
            double v = (double)data[(b * NN + n) * WW + w];
            s += v; s2 += v * v;
        }
        for (int off = 32; off; off >>= 1) {
            s += __shfl_down(s, off);
            s2 += __shfl_down(s2, off);
        }
        __shared__ double redm[4], redq[4];
        if (lane == 0) { redm[wid] = s; redq[wid] = s2; }
        __syncthreads();
        if (t == 0) {
            double S = redm[0] + redm[1] + redm[2] + redm[3];
            double S2 = redq[0] + redq[1] + redq[2] + redq[3];
            double m = S / (double)LL;
            mean[n] = m;
            diagc[n] = S2 - (double)LL * m * m;   // = sum((x-m)^2)
        }
    } else {
        // ---------------- emb stats path ----------------
        int n = (pb - NN) * 2 + (t >> 7);
        int d = t & 127;
        float e = emb[n * DD + d];
        float pi = e * att_em_i[d];
        float pj = e * att_em_j[d];
        double pn = (double)e * (double)e;
        for (int off = 32; off; off >>= 1) {
            pi += __shfl_down(pi, off);
            pj += __shfl_down(pj, off);
            pn += __shfl_down(pn, off);
        }
        __shared__ float ri[4], rj[4];
        __shared__ double rn[4];
        if (lane == 0) { ri[wid] = pi; rj[wid] = pj; rn[wid] = pn; }
        __syncthreads();
        if ((t & 127) == 0) {
            int w0 = (t >> 7) * 2;
            eemi[n] = ri[w0] + ri[w0 + 1];
            eemj[n] = rj[w0] + rj[w0 + 1];
            nrm2[n] = rn[w0] + rn[w0 + 1];
        }
    }
}

// ================= Kernel 2: inline row-reduce + sim + rank-select top-20 =================
// Block i, thread t owns cell (i,t). Row cells for (i>=128, t<128) live transposed in
// tile (0,1): read covp[z][t][i]. Diagonal (std) from fp64 diagc[] (mean path).
__global__ void k_simtopk2(const float* __restrict__ covp,
                           const double* __restrict__ mean,
                           const double* __restrict__ diagc,
                           const float* __restrict__ emb,
                           const double* __restrict__ nrm2,
                           int* __restrict__ topk, int split) {
    int i = blockIdx.x;
    int t = threadIdx.x;                  // 256 threads
    __shared__ float embI[DD];
    __shared__ float sim[NN];

    if (t < DD) embI[t] = emb[i * DD + t];

    // fp64 sum of fp32 chunk partials for cov cell (i,t)
    size_t base = (i < 128 || t >= 128) ? ((size_t)i * NN + t) : ((size_t)t * NN + i);
    double s = 0.0;
    for (int z = 0; z < split; ++z) s += (double)covp[(size_t)z * NN * NN + base];
    s -= (double)LL * mean[i] * mean[t];

    __syncthreads();                      // embI ready

    const float4* er = (const float4*)(emb + (size_t)t * DD);
    double dot = 0.0;
    #pragma unroll 8
    for (int d4 = 0; d4 < DD / 4; ++d4) {
        float4 v = er[d4];
        dot += (double)embI[4 * d4 + 0] * (double)v.x
             + (double)embI[4 * d4 + 1] * (double)v.y
             + (double)embI[4 * d4 + 2] * (double)v.z
             + (double)embI[4 * d4 + 3] * (double)v.w;
    }
    double cosv = dot / (sqrt(nrm2[i]) * sqrt(nrm2[t]) + 1e-8);
    double stdi = sqrt(diagc[i] + 1e-8);
    double stdj = sqrt(diagc[t] + 1e-8);
    double corrv = s / (stdi * stdj + 1e-8);
    sim[t] = (float)(0.7 * cosv + 0.3 * corrv);
    __syncthreads();

    // rank = # elements strictly ahead in (value desc, index asc) order
    float my = sim[t];
    int cnt = 0;
    #pragma unroll 8
    for (int u = 0; u < NN; ++u) {
        float sv = sim[u];                // uniform addr -> LDS broadcast
        cnt += (sv > my || (sv == my && u < t)) ? 1 : 0;
    }
    if (cnt < KK) topk[i * KK + cnt] = t;
}

// ================= Kernel 3: fused attention (eem terms added here) =================
__global__ __launch_bounds__(512) void k_attn3(
        const float* __restrict__ xl, const int* __restrict__ topk,
        const float* __restrict__ sil, const float* __restrict__ sjl,
        const float* __restrict__ eemi, const float* __restrict__ eemj,
        const float* __restrict__ gnn_bias,
        const float* __restrict__ bn1_g, const float* __restrict__ bn1_b,
        const float* __restrict__ bn2_g, const float* __restrict__ bn2_b,
        const float* __restrict__ emb,
        const float* __restrict__ outW, const float* __restrict__ outb,
        float* __restrict__ out) {
    const int h = blockIdx.x;             // node half: 0 or 1
    const int b = blockIdx.y;             // batch
    const int t = threadIdx.x;            // 512 threads = 8 waves
    const int lane = t & 63, wv = t >> 6;
    const int q = lane & 31, half = lane >> 5;

    __shared__ float xls[NN * DD];        // 128 KB: xl[b]
    __shared__ int2 jwS[128 * KK];        // 20 KB

    {
        const float4* src = (const float4*)(xl + (size_t)b * NN * DD);
        float4* dst = (float4*)xls;
        #pragma unroll
        for (int e = 0; e < 16; ++e) dst[t + e * 512] = src[t + e * 512];
    }

    if (t < 128) {
        int i = h * 128 + t;
        float si = sil[b * NN + i] + eemi[i];
        int jj[KK]; float aa[KK];
        float amax = -3.4e38f;
        #pragma unroll
        for (int k = 0; k < KK; ++k) {
            int j = topk[i * KK + k];
            jj[k] = j;
            float a = si + sjl[b * NN + j] + eemj[j];
            a = a > 0.f ? a : 0.2f * a;   // leaky relu
            aa[k] = a;
            amax = fmaxf(amax, a);
        }
        float den = 0.f;
        #pragma unroll
        for (int k = 0; k < KK; ++k) { float e = expf(aa[k] - amax); aa[k] = e; den += e; }
        float r = 1.f / den;
        #pragma unroll
        for (int k = 0; k < KK; ++k)
            jwS[t * KK + k] = make_int2(jj[k], __float_as_int(aa[k] * r));
    }
    __syncthreads();

    const float rbnd = 1.0f / sqrtf(1.0f + 1e-5f);
    const float4 gb = ((const float4*)gnn_bias)[q];
    const float4 g1 = ((const float4*)bn1_g)[q];
    const float4 b1 = ((const float4*)bn1_b)[q];
    const float4 g2 = ((const float4*)bn2_g)[q];
    const float4 b2 = ((const float4*)bn2_b)[q];
    const float4 ow = ((const float4*)outW)[q];
    const float ob0 = outb[0];

    for (int n = 0; n < 8; ++n) {
        int il = wv * 16 + 2 * n + half;  // local node 0..127
        int i  = h * 128 + il;

        float ax = 0.f, ay = 0.f, az = 0.f, aw = 0.f;
        #pragma unroll
        for (int k = 0; k < KK; ++k) {
            int2 p = jwS[il * KK + k];
            float w = __int_as_float(p.y);
            float4 xv = *(const float4*)&xls[p.x * DD + 4 * q];
            ax += w * xv.x; ay += w * xv.y; az += w * xv.z; aw += w * xv.w;
        }

        float4 em = *(const float4*)&emb[(size_t)i * DD + 4 * q];
        float o0 = (ax + gb.x) * rbnd * g1.x + b1.x; o0 = fmaxf(o0, 0.f);
        float o1 = (ay + gb.y) * rbnd * g1.y + b1.y; o1 = fmaxf(o1, 0.f);
        float o2 = (az + gb.z) * rbnd * g1.z + b1.z; o2 = fmaxf(o2, 0.f);
        float o3 = (aw + gb.w) * rbnd * g1.w + b1.w; o3 = fmaxf(o3, 0.f);
        float h0 = o0 * em.x * rbnd * g2.x + b2.x; h0 = fmaxf(h0, 0.f);
        float h1 = o1 * em.y * rbnd * g2.y + b2.y; h1 = fmaxf(h1, 0.f);
        float h2 = o2 * em.z * rbnd * g2.z + b2.z; h2 = fmaxf(h2, 0.f);
        float h3 = o3 * em.w * rbnd * g2.w + b2.w; h3 = fmaxf(h3, 0.f);

        float p4 = h0 * ow.x + h1 * ow.y + h2 * ow.z + h3 * ow.w;
        #pragma unroll
        for (int off = 16; off; off >>= 1) p4 += __shfl_xor(p4, off);
        if (q == 0) out[b * NN + i] = p4 + ob0;
    }
}

extern "C" void kernel_launch(void* const* d_in, const int* in_sizes, int n_in,
                              void* d_out, int out_size, void* d_ws, size_t ws_size,
                              hipStream_t stream) {
    const float* data     = (const float*)d_in[0];
    // d_in[1] = org_edge_index (unused, as in reference)
    const float* emb      = (const float*)d_in[2];
    const float* linW     = (const float*)d_in[3];
    const float* att_i    = (const float*)d_in[4];
    const float* att_j    = (const float*)d_in[5];
    const float* att_em_i = (const float*)d_in[6];
    const float* att_em_j = (const float*)d_in[7];
    const float* gnn_bias = (const float*)d_in[8];
    const float* bn1_g    = (const float*)d_in[9];
    const float* bn1_b    = (const float*)d_in[10];
    const float* bn2_g    = (const float*)d_in[11];
    const float* bn2_b    = (const float*)d_in[12];
    const float* outW     = (const float*)d_in[13];
    const float* outb     = (const float*)d_in[14];
    float* out = (float*)d_out;

    char* ws = (char*)d_ws;
    double* mean  = (double*)(ws + 0);                        // 2 KB
    double* nrm2  = (double*)(ws + 2048);                     // 2 KB
    float*  eemi  = (float*)(ws + 4096);                      // 1 KB
    float*  eemj  = (float*)(ws + 5120);                      // 1 KB
    double* diagc = (double*)(ws + 6144);                     // 2 KB
    int*    topk  = (int*)(ws + 8192);                        // 20 KB
    float*  sil   = (float*)(ws + (64 << 10));                // 128 KB
    float*  sjl   = (float*)(ws + (192 << 10));               // 128 KB
    float*  covp  = (float*)(ws + (1 << 20));                 // split*256KB (33.5 MB @128)
    float*  xl    = (float*)(ws + (36 << 20));                // 16 MB

    // split=128 needs covp 33.5 MB (+ xl to 52 MB); fall back to 64 on small ws.
    int split = (ws_size >= (size_t)(53 << 20)) ? 128 : 64;
    int bpc = BB / split;

    k_mega<<<3 * split + 256 + 256 + 128, 256, 0, stream>>>(
        data, emb, linW, att_i, att_j, att_em_i, att_em_j,
        covp, mean, diagc, eemi, eemj, nrm2, xl, sil, sjl, split, bpc);
    k_simtopk2<<<NN, 256, 0, stream>>>(covp, mean, diagc, emb, nrm2, topk, split);
    dim3 ga(2, BB);
    k_attn3<<<ga, 512, 0, stream>>>(xl, topk, sil, sjl, eemi, eemj, gnn_bias,
                                    bn1_g, bn1_b, bn2_g, bn2_b, emb, outW, outb, out);
}

// Round 14
// 124.094 us; speedup vs baseline: 1.1774x; 1.1774x over previous
//
#include <hip/hip_runtime.h>
#include <math.h>

#define BB 128
#define NN 256
#define WW 64
#define DD 128
#define KK 20
#define LL (BB*WW)   // 8192

// ================= Kernel 1: cov partials, STANDALONE (regalloc isolation) =================
// 6 upper-triangle 128x64 tiles x split chunks; acc[8][4] fp32/thread; 52 KB LDS ->
// exactly 3 blocks/CU, grid 768 = 3/CU uniform. (Round-13 post-mortem: fusing two
// acc[8][8] paths unioned regalloc to 256 VGPR -> 2 waves/SIMD; keep this kernel alone.)
__global__ __launch_bounds__(256) void k_cov(const float* __restrict__ data,
                                             float* __restrict__ covp, int bpc) {
    // tiles: (row128, col64): (0,0)(0,1)(0,2)(0,3)(1,2)(1,3) — covers i<128 all j, and
    // i>=128 j>=128; lower-left read transposed in k_simtopk2.
    const int rowtab[6] = {0, 0, 0, 0, 1, 1};
    const int coltab[6] = {0, 1, 2, 3, 2, 3};
    const int tile = blockIdx.x;          // 0..5
    const int bz = blockIdx.y;            // 0..split-1
    const int i0 = rowtab[tile] * 128;
    const int j0 = coltab[tile] * 64;
    const int t = threadIdx.x;            // 256 threads
    const int ti = t >> 4, tj = t & 15;   // rows 8*ti+r, cols tj+16*c

    __shared__ float As[128][68];         // 34 KB
    __shared__ float Bs[64][68];          // 17 KB

    float acc[8][4] = {};
    const int b0 = bz * bpc;

    #pragma unroll 1
    for (int cb = 0; cb < bpc; ++cb) {
        const int b = b0 + cb;
        #pragma unroll
        for (int e = 0; e < 8; ++e) {
            int idx = t + e * 256, row = idx >> 4, q = idx & 15;
            *(float4*)&As[row][4 * q] =
                ((const float4*)(data + ((size_t)b * NN + i0 + row) * WW))[q];
        }
        #pragma unroll
        for (int e = 0; e < 4; ++e) {
            int idx = t + e * 256, row = idx >> 4, q = idx & 15;
            *(float4*)&Bs[row][4 * q] =
                ((const float4*)(data + ((size_t)b * NN + j0 + row) * WW))[q];
        }
        __syncthreads();

        #pragma unroll
        for (int q = 0; q < 16; ++q) {
            float4 wb[4];
            #pragma unroll
            for (int c = 0; c < 4; ++c) wb[c] = *(const float4*)&Bs[tj + 16 * c][4 * q];
            #pragma unroll
            for (int r = 0; r < 8; ++r) {
                float4 xa = *(const float4*)&As[8 * ti + r][4 * q];
                #pragma unroll
                for (int c = 0; c < 4; ++c)
                    acc[r][c] += xa.x * wb[c].x + xa.y * wb[c].y
                               + xa.z * wb[c].z + xa.w * wb[c].w;
            }
        }
        __syncthreads();
    }

    #pragma unroll
    for (int r = 0; r < 8; ++r)
        #pragma unroll
        for (int c = 0; c < 4; ++c)
            covp[((size_t)bz * NN + i0 + 8 * ti + r) * NN + j0 + tj + 16 * c] = acc[r][c];
}

// ================= Kernel 2: xl GEMM + raw att dots (blocks 0..255)
//                  + mean/diag fp64 (256..511) + emb stats (512..639) =================
// One big-acc GEMM path only (round-12 phase2 precedent: compiles ~130 VGPR, no spill).
__global__ __launch_bounds__(256) void k_phase2b(const float* __restrict__ data,
                                                 const float* __restrict__ emb,
                                                 const float* __restrict__ linW,
                                                 const float* __restrict__ att_i,
                                                 const float* __restrict__ att_j,
                                                 const float* __restrict__ att_em_i,
                                                 const float* __restrict__ att_em_j,
                                                 double* __restrict__ mean,
                                                 double* __restrict__ diagc,
                                                 float* __restrict__ eemi,
                                                 float* __restrict__ eemj,
                                                 double* __restrict__ nrm2,
                                                 float* __restrict__ xl,
                                                 float* __restrict__ sil,
                                                 float* __restrict__ sjl) {
    __shared__ float Xs[128][68];
    __shared__ float Wt[DD][68];
    const int t = threadIdx.x;            // 256 threads
    const int bx = blockIdx.x;

    if (bx < NN) {
        // ---------------- xl + raw att-dots path ----------------
        const int r0 = bx * 128;
        const int ti = t >> 4, tj = t & 15;

        #pragma unroll
        for (int e = 0; e < 8; ++e) {
            int idx = t + e * 256, row = idx >> 4, q = idx & 15;
            *(float4*)&Xs[row][4 * q] =
                ((const float4*)(data + (size_t)(r0 + row) * WW))[q];
        }
        #pragma unroll
        for (int e = 0; e < 32; ++e) {
            int idx = t + e * 256;        // idx = k*128 + col
            int k = idx >> 7, col = idx & 127;
            Wt[col][k] = linW[idx];
        }
        __syncthreads();

        float acc[8][8] = {};             // rows 8*ti+r, cols tj+16*c
        #pragma unroll
        for (int q = 0; q < 16; ++q) {
            float4 wb[8];
            #pragma unroll
            for (int c = 0; c < 8; ++c) wb[c] = *(const float4*)&Wt[tj + 16 * c][4 * q];
            #pragma unroll
            for (int r = 0; r < 8; ++r) {
                float4 xa = *(const float4*)&Xs[8 * ti + r][4 * q];
                #pragma unroll
                for (int c = 0; c < 8; ++c)
                    acc[r][c] += xa.x * wb[c].x + xa.y * wb[c].y
                               + xa.z * wb[c].z + xa.w * wb[c].w;
            }
        }
        #pragma unroll
        for (int r = 0; r < 8; ++r)
            #pragma unroll
            for (int c = 0; c < 8; ++c)
                xl[(size_t)(r0 + 8 * ti + r) * DD + tj + 16 * c] = acc[r][c];

        float ai[8], aj[8];
        #pragma unroll
        for (int c = 0; c < 8; ++c) { ai[c] = att_i[tj + 16 * c]; aj[c] = att_j[tj + 16 * c]; }
        #pragma unroll
        for (int r = 0; r < 8; ++r) {
            float pi = 0.f, pj = 0.f;
            #pragma unroll
            for (int c = 0; c < 8; ++c) { pi += acc[r][c] * ai[c]; pj += acc[r][c] * aj[c]; }
            #pragma unroll
            for (int m = 8; m; m >>= 1) { pi += __shfl_xor(pi, m); pj += __shfl_xor(pj, m); }
            if (tj == 0) {
                int v = r0 + 8 * ti + r;
                sil[v] = pi;              // eem added in k_attn3
                sjl[v] = pj;
            }
        }
        return;
    }

    const int pb = bx - NN;
    const int lane = t & 63, wid = t >> 6;
    if (pb < NN) {
        // ---------------- mean + diag path (fp64) ----------------
        int n = pb;
        double s = 0.0, s2 = 0.0;
        for (int c = 0; c < LL / 256; ++c) {
            int l = t + c * 256;
            int b = l >> 6, w = l & 63;
            double v = (double)data[(b * NN + n) * WW + w];
            s += v; s2 += v * v;
        }
        for (int off = 32; off; off >>= 1) {
            s += __shfl_down(s, off);
            s2 += __shfl_down(s2, off);
        }
        __shared__ double redm[4], redq[4];
        if (lane == 0) { redm[wid] = s; redq[wid] = s2; }
        __syncthreads();
        if (t == 0) {
            double S = redm[0] + redm[1] + redm[2] + redm[3];
            double S2 = redq[0] + redq[1] + redq[2] + redq[3];
            double m = S / (double)LL;
            mean[n] = m;
            diagc[n] = S2 - (double)LL * m * m;   // = sum((x-m)^2)
        }
    } else {
        // ---------------- emb stats path ----------------
        int n = (pb - NN) * 2 + (t >> 7);
        int d = t & 127;
        float e = emb[n * DD + d];
        float pi = e * att_em_i[d];
        float pj = e * att_em_j[d];
        double pn = (double)e * (double)e;
        for (int off = 32; off; off >>= 1) {
            pi += __shfl_down(pi, off);
            pj += __shfl_down(pj, off);
            pn += __shfl_down(pn, off);
        }
        __shared__ float ri[4], rj[4];
        __shared__ double rn[4];
        if (lane == 0) { ri[wid] = pi; rj[wid] = pj; rn[wid] = pn; }
        __syncthreads();
        if ((t & 127) == 0) {
            int w0 = (t >> 7) * 2;
            eemi[n] = ri[w0] + ri[w0 + 1];
            eemj[n] = rj[w0] + rj[w0 + 1];
            nrm2[n] = rn[w0] + rn[w0 + 1];
        }
    }
}

// ================= Kernel 3: inline row-reduce + sim + rank-select top-20 =================
__global__ void k_simtopk2(const float* __restrict__ covp,
                           const double* __restrict__ mean,
                           const double* __restrict__ diagc,
                           const float* __restrict__ emb,
                           const double* __restrict__ nrm2,
                           int* __restrict__ topk, int split) {
    int i = blockIdx.x;
    int t = threadIdx.x;                  // 256 threads
    __shared__ float embI[DD];
    __shared__ float sim[NN];

    if (t < DD) embI[t] = emb[i * DD + t];

    // fp64 sum of fp32 chunk partials for cov cell (i,t); lower-left read transposed
    size_t base = (i < 128 || t >= 128) ? ((size_t)i * NN + t) : ((size_t)t * NN + i);
    double s = 0.0;
    for (int z = 0; z < split; ++z) s += (double)covp[(size_t)z * NN * NN + base];
    s -= (double)LL * mean[i] * mean[t];

    __syncthreads();                      // embI ready

    const float4* er = (const float4*)(emb + (size_t)t * DD);
    double dot = 0.0;
    #pragma unroll 8
    for (int d4 = 0; d4 < DD / 4; ++d4) {
        float4 v = er[d4];
        dot += (double)embI[4 * d4 + 0] * (double)v.x
             + (double)embI[4 * d4 + 1] * (double)v.y
             + (double)embI[4 * d4 + 2] * (double)v.z
             + (double)embI[4 * d4 + 3] * (double)v.w;
    }
    double cosv = dot / (sqrt(nrm2[i]) * sqrt(nrm2[t]) + 1e-8);
    double stdi = sqrt(diagc[i] + 1e-8);
    double stdj = sqrt(diagc[t] + 1e-8);
    double corrv = s / (stdi * stdj + 1e-8);
    sim[t] = (float)(0.7 * cosv + 0.3 * corrv);
    __syncthreads();

    float my = sim[t];
    int cnt = 0;
    #pragma unroll 8
    for (int u = 0; u < NN; ++u) {
        float sv = sim[u];                // uniform addr -> LDS broadcast
        cnt += (sv > my || (sv == my && u < t)) ? 1 : 0;
    }
    if (cnt < KK) topk[i * KK + cnt] = t;
}

// ================= Kernel 4: fused attention (eem terms added here) =================
__global__ __launch_bounds__(512) void k_attn3(
        const float* __restrict__ xl, const int* __restrict__ topk,
        const float* __restrict__ sil, const float* __restrict__ sjl,
        const float* __restrict__ eemi, const float* __restrict__ eemj,
        const float* __restrict__ gnn_bias,
        const float* __restrict__ bn1_g, const float* __restrict__ bn1_b,
        const float* __restrict__ bn2_g, const float* __restrict__ bn2_b,
        const float* __restrict__ emb,
        const float* __restrict__ outW, const float* __restrict__ outb,
        float* __restrict__ out) {
    const int h = blockIdx.x;             // node half: 0 or 1
    const int b = blockIdx.y;             // batch
    const int t = threadIdx.x;            // 512 threads = 8 waves
    const int lane = t & 63, wv = t >> 6;
    const int q = lane & 31, half = lane >> 5;

    __shared__ float xls[NN * DD];        // 128 KB: xl[b]
    __shared__ int2 jwS[128 * KK];        // 20 KB

    {
        const float4* src = (const float4*)(xl + (size_t)b * NN * DD);
        float4* dst = (float4*)xls;
        #pragma unroll
        for (int e = 0; e < 16; ++e) dst[t + e * 512] = src[t + e * 512];
    }

    if (t < 128) {
        int i = h * 128 + t;
        float si = sil[b * NN + i] + eemi[i];
        int jj[KK]; float aa[KK];
        float amax = -3.4e38f;
        #pragma unroll
        for (int k = 0; k < KK; ++k) {
            int j = topk[i * KK + k];
            jj[k] = j;
            float a = si + sjl[b * NN + j] + eemj[j];
            a = a > 0.f ? a : 0.2f * a;   // leaky relu
            aa[k] = a;
            amax = fmaxf(amax, a);
        }
        float den = 0.f;
        #pragma unroll
        for (int k = 0; k < KK; ++k) { float e = expf(aa[k] - amax); aa[k] = e; den += e; }
        float r = 1.f / den;
        #pragma unroll
        for (int k = 0; k < KK; ++k)
            jwS[t * KK + k] = make_int2(jj[k], __float_as_int(aa[k] * r));
    }
    __syncthreads();

    const float rbnd = 1.0f / sqrtf(1.0f + 1e-5f);
    const float4 gb = ((const float4*)gnn_bias)[q];
    const float4 g1 = ((const float4*)bn1_g)[q];
    const float4 b1 = ((const float4*)bn1_b)[q];
    const float4 g2 = ((const float4*)bn2_g)[q];
    const float4 b2 = ((const float4*)bn2_b)[q];
    const float4 ow = ((const float4*)outW)[q];
    const float ob0 = outb[0];

    for (int n = 0; n < 8; ++n) {
        int il = wv * 16 + 2 * n + half;  // local node 0..127
        int i  = h * 128 + il;

        float ax = 0.f, ay = 0.f, az = 0.f, aw = 0.f;
        #pragma unroll
        for (int k = 0; k < KK; ++k) {
            int2 p = jwS[il * KK + k];
            float w = __int_as_float(p.y);
            float4 xv = *(const float4*)&xls[p.x * DD + 4 * q];
            ax += w * xv.x; ay += w * xv.y; az += w * xv.z; aw += w * xv.w;
        }

        float4 em = *(const float4*)&emb[(size_t)i * DD + 4 * q];
        float o0 = (ax + gb.x) * rbnd * g1.x + b1.x; o0 = fmaxf(o0, 0.f);
        float o1 = (ay + gb.y) * rbnd * g1.y + b1.y; o1 = fmaxf(o1, 0.f);
        float o2 = (az + gb.z) * rbnd * g1.z + b1.z; o2 = fmaxf(o2, 0.f);
        float o3 = (aw + gb.w) * rbnd * g1.w + b1.w; o3 = fmaxf(o3, 0.f);
        float h0 = o0 * em.x * rbnd * g2.x + b2.x; h0 = fmaxf(h0, 0.f);
        float h1 = o1 * em.y * rbnd * g2.y + b2.y; h1 = fmaxf(h1, 0.f);
        float h2 = o2 * em.z * rbnd * g2.z + b2.z; h2 = fmaxf(h2, 0.f);
        float h3 = o3 * em.w * rbnd * g2.w + b2.w; h3 = fmaxf(h3, 0.f);

        float p4 = h0 * ow.x + h1 * ow.y + h2 * ow.z + h3 * ow.w;
        #pragma unroll
        for (int off = 16; off; off >>= 1) p4 += __shfl_xor(p4, off);
        if (q == 0) out[b * NN + i] = p4 + ob0;
    }
}

extern "C" void kernel_launch(void* const* d_in, const int* in_sizes, int n_in,
                              void* d_out, int out_size, void* d_ws, size_t ws_size,
                              hipStream_t stream) {
    const float* data     = (const float*)d_in[0];
    // d_in[1] = org_edge_index (unused, as in reference)
    const float* emb      = (const float*)d_in[2];
    const float* linW     = (const float*)d_in[3];
    const float* att_i    = (const float*)d_in[4];
    const float* att_j    = (const float*)d_in[5];
    const float* att_em_i = (const float*)d_in[6];
    const float* att_em_j = (const float*)d_in[7];
    const float* gnn_bias = (const float*)d_in[8];
    const float* bn1_g    = (const float*)d_in[9];
    const float* bn1_b    = (const float*)d_in[10];
    const float* bn2_g    = (const float*)d_in[11];
    const float* bn2_b    = (const float*)d_in[12];
    const float* outW     = (const float*)d_in[13];
    const float* outb     = (const float*)d_in[14];
    float* out = (float*)d_out;

    char* ws = (char*)d_ws;
    double* mean  = (double*)(ws + 0);                        // 2 KB
    double* nrm2  = (double*)(ws + 2048);                     // 2 KB
    float*  eemi  = (float*)(ws + 4096);                      // 1 KB
    float*  eemj  = (float*)(ws + 5120);                      // 1 KB
    double* diagc = (double*)(ws + 6144);                     // 2 KB
    int*    topk  = (int*)(ws + 8192);                        // 20 KB
    float*  sil   = (float*)(ws + (64 << 10));                // 128 KB
    float*  sjl   = (float*)(ws + (192 << 10));               // 128 KB
    float*  covp  = (float*)(ws + (1 << 20));                 // split*256KB (33.5 MB @128)
    float*  xl    = (float*)(ws + (36 << 20));                // 16 MB

    int split = (ws_size >= (size_t)(53 << 20)) ? 128 : 64;
    int bpc = BB / split;

    dim3 gcov(6, split);
    k_cov<<<gcov, 256, 0, stream>>>(data, covp, bpc);
    k_phase2b<<<NN + NN + NN / 2, 256, 0, stream>>>(
        data, emb, linW, att_i, att_j, att_em_i, att_em_j,
        mean, diagc, eemi, eemj, nrm2, xl, sil, sjl);
    k_simtopk2<<<NN, 256, 0, stream>>>(covp, mean, diagc, emb, nrm2, topk, split);
    dim3 ga(2, BB);
    k_attn3<<<ga, 512, 0, stream>>>(xl, topk, sil, sjl, eemi, eemj, gnn_bias,
                                    bn1_g, bn1_b, bn2_g, bn2_b, emb, outW, outb, out);
}

// Round 15
// 87.086 us; speedup vs baseline: 1.6777x; 1.4250x over previous
//
#include <hip/hip_runtime.h>
#include <math.h>

#define BB 128
#define NN 256
#define WW 64
#define DD 128
#define KK 20
#define LL (BB*WW)   // 8192

// ================= Kernel 1: cov partial tiles + mean/diag + emb stats =================
// blocks [0, 6*split): 128x64 upper-tri cov tiles, acc[8][4] fp32 (~100 VGPR — safe union
// with the light fp64 pre paths; round-13 lesson: never union TWO big-acc GEMMs).
// blocks [6*split, +256): mean + diag (fp64). blocks [+256, +128): emb stats.
__global__ __launch_bounds__(256) void k_cov(const float* __restrict__ data,
                                             const float* __restrict__ emb,
                                             const float* __restrict__ att_em_i,
                                             const float* __restrict__ att_em_j,
                                             float* __restrict__ covp,
                                             double* __restrict__ mean,
                                             double* __restrict__ diagc,
                                             float* __restrict__ eemi,
                                             float* __restrict__ eemj,
                                             double* __restrict__ nrm2,
                                             int split, int bpc) {
    __shared__ float As[128][68];         // 34 KB
    __shared__ float Bs[64][68];          // 17 KB
    const int t = threadIdx.x;            // 256 threads
    const int bx = blockIdx.x;
    const int ncov = 6 * split;

    if (bx < ncov) {
        // tiles (row128, col64): (0,0)(0,1)(0,2)(0,3)(1,2)(1,3); lower-left read transposed.
        const int rowtab[6] = {0, 0, 0, 0, 1, 1};
        const int coltab[6] = {0, 1, 2, 3, 2, 3};
        const int tile = bx % 6, bz = bx / 6;
        const int i0 = rowtab[tile] * 128;
        const int j0 = coltab[tile] * 64;
        const int ti = t >> 4, tj = t & 15;

        float acc[8][4] = {};
        const int b0 = bz * bpc;

        #pragma unroll 1
        for (int cb = 0; cb < bpc; ++cb) {
            const int b = b0 + cb;
            #pragma unroll
            for (int e = 0; e < 8; ++e) {
                int idx = t + e * 256, row = idx >> 4, q = idx & 15;
                *(float4*)&As[row][4 * q] =
                    ((const float4*)(data + ((size_t)b * NN + i0 + row) * WW))[q];
            }
            #pragma unroll
            for (int e = 0; e < 4; ++e) {
                int idx = t + e * 256, row = idx >> 4, q = idx & 15;
                *(float4*)&Bs[row][4 * q] =
                    ((const float4*)(data + ((size_t)b * NN + j0 + row) * WW))[q];
            }
            __syncthreads();

            #pragma unroll
            for (int q = 0; q < 16; ++q) {
                float4 wb[4];
                #pragma unroll
                for (int c = 0; c < 4; ++c) wb[c] = *(const float4*)&Bs[tj + 16 * c][4 * q];
                #pragma unroll
                for (int r = 0; r < 8; ++r) {
                    float4 xa = *(const float4*)&As[8 * ti + r][4 * q];
                    #pragma unroll
                    for (int c = 0; c < 4; ++c)
                        acc[r][c] += xa.x * wb[c].x + xa.y * wb[c].y
                                   + xa.z * wb[c].z + xa.w * wb[c].w;
                }
            }
            __syncthreads();
        }

        #pragma unroll
        for (int r = 0; r < 8; ++r)
            #pragma unroll
            for (int c = 0; c < 4; ++c)
                covp[((size_t)bz * NN + i0 + 8 * ti + r) * NN + j0 + tj + 16 * c] = acc[r][c];
        return;
    }

    const int pb = bx - ncov;
    const int lane = t & 63, wid = t >> 6;
    if (pb < NN) {
        // ---------------- mean + diag path (fp64) ----------------
        int n = pb;
        double s = 0.0, s2 = 0.0;
        for (int c = 0; c < LL / 256; ++c) {
            int l = t + c * 256;
            int b = l >> 6, w = l & 63;
            double v = (double)data[(b * NN + n) * WW + w];
            s += v; s2 += v * v;
        }
        for (int off = 32; off; off >>= 1) {
            s += __shfl_down(s, off);
            s2 += __shfl_down(s2, off);
        }
        __shared__ double redm[4], redq[4];
        if (lane == 0) { redm[wid] = s; redq[wid] = s2; }
        __syncthreads();
        if (t == 0) {
            double S = redm[0] + redm[1] + redm[2] + redm[3];
            double S2 = redq[0] + redq[1] + redq[2] + redq[3];
            double m = S / (double)LL;
            mean[n] = m;
            diagc[n] = S2 - (double)LL * m * m;   // = sum((x-m)^2)
        }
    } else {
        // ---------------- emb stats path ----------------
        int n = (pb - NN) * 2 + (t >> 7);
        int d = t & 127;
        float e = emb[n * DD + d];
        float pi = e * att_em_i[d];
        float pj = e * att_em_j[d];
        double pn = (double)e * (double)e;
        for (int off = 32; off; off >>= 1) {
            pi += __shfl_down(pi, off);
            pj += __shfl_down(pj, off);
            pn += __shfl_down(pn, off);
        }
        __shared__ float ri[4], rj[4];
        __shared__ double rn[4];
        if (lane == 0) { ri[wid] = pi; rj[wid] = pj; rn[wid] = pn; }
        __syncthreads();
        if ((t & 127) == 0) {
            int w0 = (t >> 7) * 2;
            eemi[n] = ri[w0] + ri[w0 + 1];
            eemj[n] = rj[w0] + rj[w0 + 1];
            nrm2[n] = rn[w0] + rn[w0 + 1];
        }
    }
}

// ================= Kernel 2: xl GEMM + raw att dots (blocks 0..255)
//                  + covp z-reduce -> cov fp64 (blocks 256..511) =================
// Reduce blocks co-resident with GEMM blocks (their HBM latency hides under GEMM compute,
// round-12 precedent) AND 8 independent accumulators (8 loads in flight — round-14's
// 55 µs simtopk was a single-accumulator serial chain at 1 block/CU).
__global__ __launch_bounds__(256) void k_phase2(const float* __restrict__ data,
                                                const float* __restrict__ linW,
                                                const float* __restrict__ att_i,
                                                const float* __restrict__ att_j,
                                                const float* __restrict__ covp,
                                                const double* __restrict__ mean,
                                                double* __restrict__ cov,
                                                float* __restrict__ xl,
                                                float* __restrict__ sil,
                                                float* __restrict__ sjl,
                                                int split) {
    __shared__ float Xs[128][68];
    __shared__ float Wt[DD][68];
    const int t = threadIdx.x;            // 256 threads
    const int bx = blockIdx.x;

    if (bx >= NN) {
        // ---------------- covp z-reduce path ----------------
        int cell = (bx - NN) * 256 + t;   // 0..65535
        int i = cell >> 8, j = cell & 255;
        size_t base = (i < 128 || j >= 128) ? ((size_t)i * NN + j) : ((size_t)j * NN + i);
        const float* p = covp + base;
        double s0 = 0, s1 = 0, s2 = 0, s3 = 0, s4 = 0, s5 = 0, s6 = 0, s7 = 0;
        const size_t NS = (size_t)NN * NN;
        for (int z = 0; z < split; z += 8) {
            const float* q = p + (size_t)z * NS;
            s0 += (double)q[0];
            s1 += (double)q[NS];
            s2 += (double)q[2 * NS];
            s3 += (double)q[3 * NS];
            s4 += (double)q[4 * NS];
            s5 += (double)q[5 * NS];
            s6 += (double)q[6 * NS];
            s7 += (double)q[7 * NS];
        }
        double s = ((s0 + s1) + (s2 + s3)) + ((s4 + s5) + (s6 + s7));
        s -= (double)LL * mean[i] * mean[j];
        cov[(size_t)i * NN + j] = s;
        return;
    }

    // ---------------- xl + raw att-dots path ----------------
    const int r0 = bx * 128;
    const int ti = t >> 4, tj = t & 15;

    #pragma unroll
    for (int e = 0; e < 8; ++e) {
        int idx = t + e * 256, row = idx >> 4, q = idx & 15;
        *(float4*)&Xs[row][4 * q] =
            ((const float4*)(data + (size_t)(r0 + row) * WW))[q];
    }
    #pragma unroll
    for (int e = 0; e < 32; ++e) {
        int idx = t + e * 256;            // idx = k*128 + col
        int k = idx >> 7, col = idx & 127;
        Wt[col][k] = linW[idx];
    }
    __syncthreads();

    float acc[8][8] = {};                 // rows 8*ti+r, cols tj+16*c
    #pragma unroll
    for (int q = 0; q < 16; ++q) {
        float4 wb[8];
        #pragma unroll
        for (int c = 0; c < 8; ++c) wb[c] = *(const float4*)&Wt[tj + 16 * c][4 * q];
        #pragma unroll
        for (int r = 0; r < 8; ++r) {
            float4 xa = *(const float4*)&Xs[8 * ti + r][4 * q];
            #pragma unroll
            for (int c = 0; c < 8; ++c)
                acc[r][c] += xa.x * wb[c].x + xa.y * wb[c].y
                           + xa.z * wb[c].z + xa.w * wb[c].w;
        }
    }
    #pragma unroll
    for (int r = 0; r < 8; ++r)
        #pragma unroll
        for (int c = 0; c < 8; ++c)
            xl[(size_t)(r0 + 8 * ti + r) * DD + tj + 16 * c] = acc[r][c];

    float ai[8], aj[8];
    #pragma unroll
    for (int c = 0; c < 8; ++c) { ai[c] = att_i[tj + 16 * c]; aj[c] = att_j[tj + 16 * c]; }
    #pragma unroll
    for (int r = 0; r < 8; ++r) {
        float pi = 0.f, pj = 0.f;
        #pragma unroll
        for (int c = 0; c < 8; ++c) { pi += acc[r][c] * ai[c]; pj += acc[r][c] * aj[c]; }
        #pragma unroll
        for (int m = 8; m; m >>= 1) { pi += __shfl_xor(pi, m); pj += __shfl_xor(pj, m); }
        if (tj == 0) {
            int v = r0 + 8 * ti + r;
            sil[v] = pi;                  // eem added in k_attn3
            sjl[v] = pj;
        }
    }
}

// ================= Kernel 3: sim + rank-select top-20 (cov materialized) =================
__global__ void k_simtopk3(const double* __restrict__ cov,
                           const double* __restrict__ diagc,
                           const float* __restrict__ emb,
                           const double* __restrict__ nrm2,
                           int* __restrict__ topk) {
    int i = blockIdx.x;
    int t = threadIdx.x;                  // 256 threads
    __shared__ float embI[DD];
    __shared__ float sim[NN];

    if (t < DD) embI[t] = emb[i * DD + t];
    double s = cov[(size_t)i * NN + t];   // single coalesced load
    __syncthreads();

    const float4* er = (const float4*)(emb + (size_t)t * DD);
    double dot = 0.0;
    #pragma unroll 8
    for (int d4 = 0; d4 < DD / 4; ++d4) {
        float4 v = er[d4];
        dot += (double)embI[4 * d4 + 0] * (double)v.x
             + (double)embI[4 * d4 + 1] * (double)v.y
             + (double)embI[4 * d4 + 2] * (double)v.z
             + (double)embI[4 * d4 + 3] * (double)v.w;
    }
    double cosv = dot / (sqrt(nrm2[i]) * sqrt(nrm2[t]) + 1e-8);
    double stdi = sqrt(diagc[i] + 1e-8);
    double stdj = sqrt(diagc[t] + 1e-8);
    double corrv = s / (stdi * stdj + 1e-8);
    sim[t] = (float)(0.7 * cosv + 0.3 * corrv);
    __syncthreads();

    float my = sim[t];
    int cnt = 0;
    #pragma unroll 8
    for (int u = 0; u < NN; ++u) {
        float sv = sim[u];                // uniform addr -> LDS broadcast
        cnt += (sv > my || (sv == my && u < t)) ? 1 : 0;
    }
    if (cnt < KK) topk[i * KK + cnt] = t;
}

// ================= Kernel 4: fused attention (eem terms added here) =================
__global__ __launch_bounds__(512) void k_attn3(
        const float* __restrict__ xl, const int* __restrict__ topk,
        const float* __restrict__ sil, const float* __restrict__ sjl,
        const float* __restrict__ eemi, const float* __restrict__ eemj,
        const float* __restrict__ gnn_bias,
        const float* __restrict__ bn1_g, const float* __restrict__ bn1_b,
        const float* __restrict__ bn2_g, const float* __restrict__ bn2_b,
        const float* __restrict__ emb,
        const float* __restrict__ outW, const float* __restrict__ outb,
        float* __restrict__ out) {
    const int h = blockIdx.x;             // node half: 0 or 1
    const int b = blockIdx.y;             // batch
    const int t = threadIdx.x;            // 512 threads = 8 waves
    const int lane = t & 63, wv = t >> 6;
    const int q = lane & 31, half = lane >> 5;

    __shared__ float xls[NN * DD];        // 128 KB: xl[b]
    __shared__ int2 jwS[128 * KK];        // 20 KB

    {
        const float4* src = (const float4*)(xl + (size_t)b * NN * DD);
        float4* dst = (float4*)xls;
        #pragma unroll
        for (int e = 0; e < 16; ++e) dst[t + e * 512] = src[t + e * 512];
    }

    if (t < 128) {
        int i = h * 128 + t;
        float si = sil[b * NN + i] + eemi[i];
        int jj[KK]; float aa[KK];
        float amax = -3.4e38f;
        #pragma unroll
        for (int k = 0; k < KK; ++k) {
            int j = topk[i * KK + k];
            jj[k] = j;
            float a = si + sjl[b * NN + j] + eemj[j];
            a = a > 0.f ? a : 0.2f * a;   // leaky relu
            aa[k] = a;
            amax = fmaxf(amax, a);
        }
        float den = 0.f;
        #pragma unroll
        for (int k = 0; k < KK; ++k) { float e = expf(aa[k] - amax); aa[k] = e; den += e; }
        float r = 1.f / den;
        #pragma unroll
        for (int k = 0; k < KK; ++k)
            jwS[t * KK + k] = make_int2(jj[k], __float_as_int(aa[k] * r));
    }
    __syncthreads();

    const float rbnd = 1.0f / sqrtf(1.0f + 1e-5f);
    const float4 gb = ((const float4*)gnn_bias)[q];
    const float4 g1 = ((const float4*)bn1_g)[q];
    const float4 b1 = ((const float4*)bn1_b)[q];
    const float4 g2 = ((const float4*)bn2_g)[q];
    const float4 b2 = ((const float4*)bn2_b)[q];
    const float4 ow = ((const float4*)outW)[q];
    const float ob0 = outb[0];

    for (int n = 0; n < 8; ++n) {
        int il = wv * 16 + 2 * n + half;  // local node 0..127
        int i  = h * 128 + il;

        float ax = 0.f, ay = 0.f, az = 0.f, aw = 0.f;
        #pragma unroll
        for (int k = 0; k < KK; ++k) {
            int2 p = jwS[il * KK + k];
            float w = __int_as_float(p.y);
            float4 xv = *(const float4*)&xls[p.x * DD + 4 * q];
            ax += w * xv.x; ay += w * xv.y; az += w * xv.z; aw += w * xv.w;
        }

        float4 em = *(const float4*)&emb[(size_t)i * DD + 4 * q];
        float o0 = (ax + gb.x) * rbnd * g1.x + b1.x; o0 = fmaxf(o0, 0.f);
        float o1 = (ay + gb.y) * rbnd * g1.y + b1.y; o1 = fmaxf(o1, 0.f);
        float o2 = (az + gb.z) * rbnd * g1.z + b1.z; o2 = fmaxf(o2, 0.f);
        float o3 = (aw + gb.w) * rbnd * g1.w + b1.w; o3 = fmaxf(o3, 0.f);
        float h0 = o0 * em.x * rbnd * g2.x + b2.x; h0 = fmaxf(h0, 0.f);
        float h1 = o1 * em.y * rbnd * g2.y + b2.y; h1 = fmaxf(h1, 0.f);
        float h2 = o2 * em.z * rbnd * g2.z + b2.z; h2 = fmaxf(h2, 0.f);
        float h3 = o3 * em.w * rbnd * g2.w + b2.w; h3 = fmaxf(h3, 0.f);

        float p4 = h0 * ow.x + h1 * ow.y + h2 * ow.z + h3 * ow.w;
        #pragma unroll
        for (int off = 16; off; off >>= 1) p4 += __shfl_xor(p4, off);
        if (q == 0) out[b * NN + i] = p4 + ob0;
    }
}

extern "C" void kernel_launch(void* const* d_in, const int* in_sizes, int n_in,
                              void* d_out, int out_size, void* d_ws, size_t ws_size,
                              hipStream_t stream) {
    const float* data     = (const float*)d_in[0];
    // d_in[1] = org_edge_index (unused, as in reference)
    const float* emb      = (const float*)d_in[2];
    const float* linW     = (const float*)d_in[3];
    const float* att_i    = (const float*)d_in[4];
    const float* att_j    = (const float*)d_in[5];
    const float* att_em_i = (const float*)d_in[6];
    const float* att_em_j = (const float*)d_in[7];
    const float* gnn_bias = (const float*)d_in[8];
    const float* bn1_g    = (const float*)d_in[9];
    const float* bn1_b    = (const float*)d_in[10];
    const float* bn2_g    = (const float*)d_in[11];
    const float* bn2_b    = (const float*)d_in[12];
    const float* outW     = (const float*)d_in[13];
    const float* outb     = (const float*)d_in[14];
    float* out = (float*)d_out;

    char* ws = (char*)d_ws;
    double* mean  = (double*)(ws + 0);                        // 2 KB
    double* nrm2  = (double*)(ws + 2048);                     // 2 KB
    float*  eemi  = (float*)(ws + 4096);                      // 1 KB
    float*  eemj  = (float*)(ws + 5120);                      // 1 KB
    double* diagc = (double*)(ws + 6144);                     // 2 KB
    int*    topk  = (int*)(ws + 8192);                        // 20 KB
    float*  sil   = (float*)(ws + (64 << 10));                // 128 KB
    float*  sjl   = (float*)(ws + (192 << 10));               // 128 KB
    double* cov   = (double*)(ws + (320 << 10));              // 512 KB
    float*  covp  = (float*)(ws + (1 << 20));                 // split*256KB (33.5 MB @128)
    float*  xl    = (float*)(ws + (36 << 20));                // 16 MB

    int split = (ws_size >= (size_t)(53 << 20)) ? 128 : 64;
    int bpc = BB / split;

    k_cov<<<6 * split + NN + NN / 2, 256, 0, stream>>>(
        data, emb, att_em_i, att_em_j, covp, mean, diagc, eemi, eemj, nrm2, split, bpc);
    k_phase2<<<2 * NN, 256, 0, stream>>>(
        data, linW, att_i, att_j, covp, mean, cov, xl, sil, sjl, split);
    k_simtopk3<<<NN, 256, 0, stream>>>(cov, diagc, emb, nrm2, topk);
    dim3 ga(2, BB);
    k_attn3<<<ga, 512, 0, stream>>>(xl, topk, sil, sjl, eemi, eemj, gnn_bias,
                                    bn1_g, bn1_b, bn2_g, bn2_b, emb, outW, outb, out);
}